// Round 11
// baseline (667.385 us; speedup 1.0000x reference)
//
#include <hip/hip_runtime.h>
#include <hip/hip_bf16.h>
#include <hip/hip_cooperative_groups.h>

namespace cg = cooperative_groups;

#define N_NODES 50000
#define N_EDGES 800000
#define FDIM 64
#define NBUCK 196                          // ceil(50000/256) buckets of 256 nodes
#define PAD 16                             // one counter per 64B line
#define NCHUNK ((N_EDGES + 1023) / 1024)   // 782 edge chunks
#define NGRP (N_NODES / 16)                // 3125 node groups of 16

typedef __attribute__((ext_vector_type(8))) short short8;
typedef __attribute__((ext_vector_type(4))) float f32x4;

// fp32 -> bf16 bits, round-to-nearest-even
__device__ __forceinline__ unsigned f2bf(float f) {
    unsigned u = __float_as_uint(f);
    u += 0x7fffu + ((u >> 16) & 1u);
    return u >> 16;
}
__device__ __forceinline__ float bf2f_lo(unsigned u) { return __uint_as_float(u << 16); }
__device__ __forceinline__ float bf2f_hi(unsigned u) { return __uint_as_float(u & 0xffff0000u); }

// shared-memory union: phases are sequential, so they share one 4KB region
union SMu {
    int hist_h[NBUCK];
    struct { int sEx[256]; int h[NBUCK]; int base[NBUCK]; } scat;
    struct { int sEx[257]; int cnt[256]; int cur[256]; } csr;
    struct { unsigned short smean[16][FDIM]; unsigned short sxs[16][FDIM]; } lay;
};

// exclusive scan of one value per thread across the 256-thread block
__device__ __forceinline__ int excl_scan_256(int v, int* wtot, int* wincl) {
    const int t = threadIdx.x, lane = t & 63, w = t >> 6;
    int sv = v;
#pragma unroll
    for (int off = 1; off < 64; off <<= 1) {
        int u = __shfl_up(sv, off, 64);
        if (lane >= off) sv += u;
    }
    if (lane == 63) wtot[w] = sv;
    __syncthreads();
    if (w == 0 && lane < 4) {
        int incl = 0;
#pragma unroll
        for (int k = 0; k < 4; ++k)
            if (k <= lane) incl += wtot[k];
        wincl[lane] = incl;
    }
    __syncthreads();
    return (w ? wincl[w - 1] : 0) + sv - v;
}

// ---------------------------------------------------------------------------
// fused SAGE layer phase (device fn): grid-strided over 3125 groups of 16 nodes.
// Phase 1 (gather): wave w: nodes 4w..4w+3; lane = q(8 edge slots) x c(8 octs);
//   16 rows in flight; mean+self rows staged in LDS bf16, octs XOR-swizzled by
//   row&7 so A-fragment reads are 2-way (free).
// Phase 2 (MFMA 16x16x32 bf16): wave ct=w does cols [16ct,16ct+16).
//   A[m=lane&15][k=(lane>>4)*8+j]; C/D: col=lane&15, row=(lane>>4)*4+reg.
// ---------------------------------------------------------------------------
template <bool OUT_BF16>
__device__ __forceinline__
void sage_layer_phase(SMu& sm,
                      const unsigned short* __restrict__ xb,
                      const int* __restrict__ row_start,
                      const unsigned short* __restrict__ csr,
                      const unsigned short* __restrict__ pWl,
                      const float* __restrict__ bl,
                      const unsigned short* __restrict__ pWr,
                      float* __restrict__ out_f32,
                      unsigned short* __restrict__ out_bf) {
    const int w = threadIdx.x >> 6;
    const int lane = threadIdx.x & 63;
    const int q = lane >> 3;
    const int c = lane & 7;

    for (int grp = blockIdx.x; grp < NGRP; grp += gridDim.x) {
        const int base = grp * 16;

        // ---- phase 1: gather 4 nodes per wave ----
#pragma unroll
        for (int i = 0; i < 4; ++i) {
            const int r = (w << 2) + i;
            const int n = base + r;
            const int rs = row_start[n];
            const int re = row_start[n + 1];
            const int po = (c ^ (r & 7)) * 8;

            float s0 = 0.f, s1 = 0.f, s2 = 0.f, s3 = 0.f,
                  s4 = 0.f, s5 = 0.f, s6 = 0.f, s7 = 0.f;

#define ADDROW(node) do {                                               \
        uint4 v_ = *(const uint4*)(xb + (size_t)(node) * FDIM + c * 8); \
        s0 += bf2f_lo(v_.x); s1 += bf2f_hi(v_.x);                       \
        s2 += bf2f_lo(v_.y); s3 += bf2f_hi(v_.y);                       \
        s4 += bf2f_lo(v_.z); s5 += bf2f_hi(v_.z);                       \
        s6 += bf2f_lo(v_.w); s7 += bf2f_hi(v_.w);                       \
    } while (0)

            if (q == 0) {                  // self row: stage + accumulate
                uint4 v_ = *(const uint4*)(xb + (size_t)n * FDIM + c * 8);
                *(uint4*)(&sm.lay.sxs[r][po]) = v_;
                s0 += bf2f_lo(v_.x); s1 += bf2f_hi(v_.x);
                s2 += bf2f_lo(v_.y); s3 += bf2f_hi(v_.y);
                s4 += bf2f_lo(v_.z); s5 += bf2f_hi(v_.z);
                s6 += bf2f_lo(v_.w); s7 += bf2f_hi(v_.w);
            }

            int idx = rs + q;
            for (; idx + 8 < re; idx += 16) {
                int a = csr[idx];
                int b2 = csr[idx + 8];
                ADDROW(a);
                ADDROW(b2);
            }
            for (; idx < re; idx += 8) ADDROW((int)csr[idx]);
#undef ADDROW

#pragma unroll
            for (int off = 8; off < 64; off <<= 1) {
                s0 += __shfl_xor(s0, off, 64);
                s1 += __shfl_xor(s1, off, 64);
                s2 += __shfl_xor(s2, off, 64);
                s3 += __shfl_xor(s3, off, 64);
                s4 += __shfl_xor(s4, off, 64);
                s5 += __shfl_xor(s5, off, 64);
                s6 += __shfl_xor(s6, off, 64);
                s7 += __shfl_xor(s7, off, 64);
            }

            if (q == 0) {
                float inv = 1.0f / (float)(re - rs + 1);
                uint4 o;
                o.x = f2bf(s0 * inv) | (f2bf(s1 * inv) << 16);
                o.y = f2bf(s2 * inv) | (f2bf(s3 * inv) << 16);
                o.z = f2bf(s4 * inv) | (f2bf(s5 * inv) << 16);
                o.w = f2bf(s6 * inv) | (f2bf(s7 * inv) << 16);
                *(uint4*)(&sm.lay.smean[r][po]) = o;
            }
        }
        __syncthreads();

        // ---- phase 2: MFMA ----
        const int ct = w;
        const int qq = lane >> 4;
        const int rr = lane & 15;

        short8 am0 = *(const short8*)(&sm.lay.smean[rr][((0 + qq) ^ (rr & 7)) * 8]);
        short8 am1 = *(const short8*)(&sm.lay.smean[rr][((4 + qq) ^ (rr & 7)) * 8]);
        short8 ax0 = *(const short8*)(&sm.lay.sxs[rr][((0 + qq) ^ (rr & 7)) * 8]);
        short8 ax1 = *(const short8*)(&sm.lay.sxs[rr][((4 + qq) ^ (rr & 7)) * 8]);

        const short8* pl = (const short8*)pWl;
        const short8* pr = (const short8*)pWr;
        short8 bl0v = pl[(ct * 2 + 0) * 64 + lane];
        short8 bl1v = pl[(ct * 2 + 1) * 64 + lane];
        short8 br0v = pr[(ct * 2 + 0) * 64 + lane];
        short8 br1v = pr[(ct * 2 + 1) * 64 + lane];

        float b = bl[ct * 16 + rr];
        f32x4 acc = {b, b, b, b};
        acc = __builtin_amdgcn_mfma_f32_16x16x32_bf16(am0, bl0v, acc, 0, 0, 0);
        acc = __builtin_amdgcn_mfma_f32_16x16x32_bf16(am1, bl1v, acc, 0, 0, 0);
        acc = __builtin_amdgcn_mfma_f32_16x16x32_bf16(ax0, br0v, acc, 0, 0, 0);
        acc = __builtin_amdgcn_mfma_f32_16x16x32_bf16(ax1, br1v, acc, 0, 0, 0);

#pragma unroll
        for (int reg = 0; reg < 4; ++reg) {
            int node = base + qq * 4 + reg;
            float v = fmaxf(acc[reg], 0.0f);
            if (OUT_BF16) out_bf[(size_t)node * FDIM + ct * 16 + rr] = (unsigned short)f2bf(v);
            else          out_f32[(size_t)node * FDIM + ct * 16 + rr] = v;
        }
        __syncthreads();   // LDS reuse by next group
    }
}

// ---------------------------------------------------------------------------
// mega kernel: entire pipeline in one cooperative launch.
// P0a zero+convert+pack | P0b histogram | P1 bucket-scatter | P2 bucket-CSR |
// P3 layer0 | P4 layer1, separated by grid.sync().
// ---------------------------------------------------------------------------
__global__ __launch_bounds__(256, 3)
void mega_kernel(const float* __restrict__ x0,
                 const int* __restrict__ src, const int* __restrict__ dst,
                 const float* __restrict__ Wl0, const float* __restrict__ bl0,
                 const float* __restrict__ Wr0,
                 const float* __restrict__ Wl1, const float* __restrict__ bl1,
                 const float* __restrict__ Wr1,
                 float* __restrict__ out, char* __restrict__ ws) {
    // workspace layout (same as round 10)
    int* bc_pad    = (int*)ws;                        // 256*PAD
    int* cur_pad   = bc_pad + 256 * PAD;              // 256*PAD
    int* row_start = cur_pad + 256 * PAD;             // 50001 -> padded 50004
    unsigned* ebuf = (unsigned*)(row_start + 50004);  // 800000
    unsigned short* csr_u16 = (unsigned short*)(ebuf + N_EDGES);  // 800000
    unsigned short* x_bf = csr_u16 + N_EDGES;
    unsigned short* h_bf = x_bf + (size_t)N_NODES * FDIM;
    unsigned short* pW   = h_bf + (size_t)N_NODES * FDIM;         // 4 x 4096

    __shared__ __align__(16) SMu sm;
    __shared__ int wtot[4], wincl[4];

    cg::grid_group grid = cg::this_grid();
    const int t = threadIdx.x;
    const int G = gridDim.x;

    // ---- P0a: zero counters; convert x0 -> bf16; pack weights ----
    for (int z = blockIdx.x * 256 + t; z < 2 * 256 * PAD; z += G * 256)
        bc_pad[z] = 0;
    for (int u = blockIdx.x; u < 3129; u += G) {
        if (u < 3125) {                    // 3125*256*4 = 3.2M exactly
            int i = (u * 256 + t) * 4;
            float4 v = *(const float4*)(x0 + i);
            uint2 o;
            o.x = f2bf(v.x) | (f2bf(v.y) << 16);
            o.y = f2bf(v.z) | (f2bf(v.w) << 16);
            *(uint2*)(x_bf + i) = o;
        } else {                           // pack W into MFMA B-fragment order
            const float* Wsrc[4] = {Wl0, Wr0, Wl1, Wr1};
            const float* W = Wsrc[u - 3125];
            unsigned short* P = pW + (u - 3125) * FDIM * FDIM;
            for (int idx = t; idx < FDIM * FDIM; idx += 256) {
                int j = idx & 7;
                int lane = (idx >> 3) & 63;
                int g = idx >> 9;          // ct*2 + kk
                int ct = g >> 1, kk = g & 1;
                int k = kk * 32 + ((lane >> 4) & 3) * 8 + j;
                int col = ct * 16 + (lane & 15);
                P[idx] = (unsigned short)f2bf(W[k * FDIM + col]);
            }
        }
    }
    grid.sync();

    // ---- P0b: bucket histogram of dst>>8 (LDS-aggregated) ----
    for (int ch = blockIdx.x; ch < NCHUNK; ch += G) {
        if (t < NBUCK) sm.hist_h[t] = 0;
        __syncthreads();
        int e0 = ch * 1024;
#pragma unroll
        for (int k = 0; k < 4; ++k) {
            int e = e0 + k * 256 + t;
            if (e < N_EDGES) atomicAdd(&sm.hist_h[dst[e] >> 8], 1);
        }
        __syncthreads();
        if (t < NBUCK) {
            int c = sm.hist_h[t];
            if (c) atomicAdd(&bc_pad[t * PAD], c);
        }
        __syncthreads();
    }
    grid.sync();

    // ---- P1: bucket scatter (packed (dst<<16)|src into bucket-ordered ebuf) ----
    {
        int v = (t < NBUCK) ? bc_pad[t * PAD] : 0;
        int ex = excl_scan_256(v, wtot, wincl);
        sm.scat.sEx[t] = ex;
        __syncthreads();
        for (int ch = blockIdx.x; ch < NCHUNK; ch += G) {
            if (t < NBUCK) sm.scat.h[t] = 0;
            __syncthreads();
            int e0 = ch * 1024;
            int bk[4], rk[4]; unsigned pk[4];
#pragma unroll
            for (int k = 0; k < 4; ++k) {
                int e = e0 + k * 256 + t;
                if (e < N_EDGES) {
                    int d = dst[e];
                    bk[k] = d >> 8;
                    pk[k] = ((unsigned)d << 16) | (unsigned)src[e];
                    rk[k] = atomicAdd(&sm.scat.h[bk[k]], 1);
                } else bk[k] = -1;
            }
            __syncthreads();
            if (t < NBUCK) {
                int c = sm.scat.h[t];
                sm.scat.base[t] = c ? (sm.scat.sEx[t] + atomicAdd(&cur_pad[t * PAD], c)) : 0;
            }
            __syncthreads();
#pragma unroll
            for (int k = 0; k < 4; ++k)
                if (bk[k] >= 0) ebuf[sm.scat.base[bk[k]] + rk[k]] = pk[k];
            __syncthreads();
        }
    }
    grid.sync();

    // ---- P2: bucket CSR finalize (row_start + csr_u16) ----
    {
        int v = (t < NBUCK) ? bc_pad[t * PAD] : 0;
        int ex = excl_scan_256(v, wtot, wincl);
        sm.csr.sEx[t] = ex;
        if (t == 255) sm.csr.sEx[256] = ex + v;
        __syncthreads();
        for (int bkt = blockIdx.x; bkt < NBUCK; bkt += G) {
            const int s = sm.csr.sEx[bkt];
            const int e = sm.csr.sEx[bkt + 1];
            sm.csr.cnt[t] = 0;
            __syncthreads();
            for (int i = s + t; i < e; i += 256)
                atomicAdd(&sm.csr.cnt[(ebuf[i] >> 16) & 255], 1);
            __syncthreads();
            int c = sm.csr.cnt[t];
            int ex2 = excl_scan_256(c, wtot, wincl);
            sm.csr.cur[t] = ex2;
            int node = bkt * 256 + t;
            if (node <= N_NODES) row_start[node] = s + ex2;
            __syncthreads();
            for (int i = s + t; i < e; i += 256) {
                unsigned pk = ebuf[i];
                int pos = s + atomicAdd(&sm.csr.cur[(pk >> 16) & 255], 1);
                csr_u16[pos] = (unsigned short)pk;
            }
            __syncthreads();
        }
    }
    grid.sync();

    // ---- P3: layer 0 (bf16 out) ----
    sage_layer_phase<true>(sm, x_bf, row_start, csr_u16,
                           pW + 0 * FDIM * FDIM, bl0, pW + 1 * FDIM * FDIM,
                           nullptr, h_bf);
    grid.sync();

    // ---- P4: layer 1 (fp32 out) ----
    sage_layer_phase<false>(sm, h_bf, row_start, csr_u16,
                            pW + 2 * FDIM * FDIM, bl1, pW + 3 * FDIM * FDIM,
                            out, nullptr);
}

// ---------------------------------------------------------------------------
extern "C" void kernel_launch(void* const* d_in, const int* in_sizes, int n_in,
                              void* d_out, int out_size, void* d_ws, size_t ws_size,
                              hipStream_t stream) {
    const float* x0  = (const float*)d_in[0];
    const int*   ei  = (const int*)d_in[1];
    const float* Wl0 = (const float*)d_in[2];
    const float* bl0 = (const float*)d_in[3];
    const float* Wr0 = (const float*)d_in[4];
    const float* Wl1 = (const float*)d_in[5];
    const float* bl1 = (const float*)d_in[6];
    const float* Wr1 = (const float*)d_in[7];
    float* out = (float*)d_out;

    const int* src = ei;            // edge_index[0]
    const int* dst = ei + N_EDGES;  // edge_index[1]
    char* ws = (char*)d_ws;

    int nb = 0;
    (void)hipOccupancyMaxActiveBlocksPerMultiprocessor(&nb, (const void*)mega_kernel, 256, 0);
    if (nb < 1) nb = 1;
    if (nb > 4) nb = 4;
    dim3 grid(nb * 256), block(256);

    void* args[] = {(void*)&x0, (void*)&src, (void*)&dst,
                    (void*)&Wl0, (void*)&bl0, (void*)&Wr0,
                    (void*)&Wl1, (void*)&bl1, (void*)&Wr1,
                    (void*)&out, (void*)&ws};
    hipLaunchCooperativeKernel((void*)mega_kernel, grid, block, args, 0, stream);
}